// Round 5
// baseline (243.501 us; speedup 1.0000x reference)
//
#include <hip/hip_runtime.h>

// 3D Spatial Transformer: trilinear grid_sample, align_corners=False,
// padding_mode='border'.  B=2, C=2, D=H=W=128, fp32.
// 4 voxels (along x) per thread: 16B nontemporal flow loads + 16B
// nontemporal output stores (both touch-once; keep L2 for image gathers).
// Indices/weights computed once per voxel, reused across both channels.
// N = D*H*W = 2^21 so index math is shifts/masks.

#define Dv 128
#define Hv 128
#define Wv 128
#define Bv 2
#define Cv 2
#define Nv (Dv * Hv * Wv)   // 2097152 = 2^21
#define Qv (Nv / 4)         // 524288  = 2^19 float4-groups per volume

// native Clang vector type — accepted by __builtin_nontemporal_{load,store}
typedef float f32x4 __attribute__((ext_vector_type(4)));

__global__ __launch_bounds__(256) void stn3d_kernel(
    const float* __restrict__ image,
    const float* __restrict__ flow,
    float* __restrict__ out)
{
    const unsigned gid = blockIdx.x * blockDim.x + threadIdx.x;  // over Bv*Qv = 2^20
    const int b = (int)(gid >> 19);
    const int q = (int)(gid & (Qv - 1));
    const int v4 = q << 2;                 // first voxel of this thread's group
    const int xb = v4 & (Wv - 1);          // x of voxel 0 (x+3 stays in-row: 4 | 128)
    const int y  = (v4 >> 7) & (Hv - 1);
    const int z  = v4 >> 14;

    // --- coalesced 16B/lane read-once flow loads (nontemporal) ---
    const float* fb = flow + (size_t)b * 3u * Nv;
    const f32x4 fx4 = __builtin_nontemporal_load((const f32x4*)(fb) + q);
    const f32x4 fy4 = __builtin_nontemporal_load((const f32x4*)(fb + Nv) + q);
    const f32x4 fz4 = __builtin_nontemporal_load((const f32x4*)(fb + 2 * Nv) + q);

    const float* ic0 = image + (size_t)b * Cv * Nv;  // channel 0 volume
    const float* ic1 = ic0 + Nv;                     // channel 1 volume

    const float step = 2.0f / 127.0f;
    const float gyb = -1.0f + step * (float)y;   // base grid (flow added per voxel)
    const float gzb = -1.0f + step * (float)z;

    f32x4 s0, s1;   // output accumulators (channel 0 / channel 1)

#pragma unroll
    for (int i = 0; i < 4; ++i) {
        // --- reference math, fp32, same op order ---
        const float gx = (-1.0f + step * (float)(xb + i)) + 2.0f * fx4[i] / 127.0f;
        const float gy = gyb + 2.0f * fy4[i] / 127.0f;
        const float gz = gzb + 2.0f * fz4[i] / 127.0f;
        float ix = ((gx + 1.0f) * (float)Wv - 1.0f) * 0.5f;
        float iy = ((gy + 1.0f) * (float)Hv - 1.0f) * 0.5f;
        float iz = ((gz + 1.0f) * (float)Dv - 1.0f) * 0.5f;
        // border padding: clip to [0, dim-1]
        ix = fminf(fmaxf(ix, 0.0f), (float)(Wv - 1));
        iy = fminf(fmaxf(iy, 0.0f), (float)(Hv - 1));
        iz = fminf(fmaxf(iz, 0.0f), (float)(Dv - 1));

        const float x0f = floorf(ix), y0f = floorf(iy), z0f = floorf(iz);
        const float tx = ix - x0f, ty = iy - y0f, tz = iz - z0f;
        const int x0 = (int)x0f, y0 = (int)y0f, z0 = (int)z0f;
        const int x1 = min(x0 + 1, Wv - 1);
        const int y1 = min(y0 + 1, Hv - 1);
        const int z1 = min(z0 + 1, Dv - 1);

        // 8 corner flat indices within one [D,H,W] volume
        const int zy00 = ((z0 << 7) + y0) << 7;
        const int zy01 = ((z0 << 7) + y1) << 7;
        const int zy10 = ((z1 << 7) + y0) << 7;
        const int zy11 = ((z1 << 7) + y1) << 7;
        const int i000 = zy00 + x0, i001 = zy00 + x1;
        const int i010 = zy01 + x0, i011 = zy01 + x1;
        const int i100 = zy10 + x0, i101 = zy10 + x1;
        const int i110 = zy11 + x0, i111 = zy11 + x1;

        const float sx = 1.0f - tx, sy = 1.0f - ty, sz = 1.0f - tz;
        const float w000 = sz * sy * sx, w001 = sz * sy * tx;
        const float w010 = sz * ty * sx, w011 = sz * ty * tx;
        const float w100 = tz * sy * sx, w101 = tz * sy * tx;
        const float w110 = tz * ty * sx, w111 = tz * ty * tx;

        // channel 0
        {
            float r = ic0[i000] * w000;
            r += ic0[i001] * w001;
            r += ic0[i010] * w010;
            r += ic0[i011] * w011;
            r += ic0[i100] * w100;
            r += ic0[i101] * w101;
            r += ic0[i110] * w110;
            r += ic0[i111] * w111;
            s0[i] = r;
        }
        // channel 1 (same indices/weights)
        {
            float r = ic1[i000] * w000;
            r += ic1[i001] * w001;
            r += ic1[i010] * w010;
            r += ic1[i011] * w011;
            r += ic1[i100] * w100;
            r += ic1[i101] * w101;
            r += ic1[i110] * w110;
            r += ic1[i111] * w111;
            s1[i] = r;
        }
    }

    // --- nontemporal 16B stores (output is write-once, keep L2 for image) ---
    float* ob = out + (size_t)b * Cv * Nv;
    __builtin_nontemporal_store(s0, (f32x4*)(ob) + q);
    __builtin_nontemporal_store(s1, (f32x4*)(ob + Nv) + q);
}

extern "C" void kernel_launch(void* const* d_in, const int* in_sizes, int n_in,
                              void* d_out, int out_size, void* d_ws, size_t ws_size,
                              hipStream_t stream) {
    const float* image = (const float*)d_in[0];
    const float* flow  = (const float*)d_in[1];
    float* out = (float*)d_out;

    const int total = Bv * Qv;            // 1,048,576 threads
    const int block = 256;
    const int grid = total / block;       // 4096 blocks
    stn3d_kernel<<<grid, block, 0, stream>>>(image, flow, out);
}